// Round 3
// baseline (752.031 us; speedup 1.0000x reference)
//
#include <hip/hip_runtime.h>

#define NFFT     4096
#define NHALF    2048
#define NHOP     1024
#define NK       2049
#define NBC      16
#define NSAMP    524288
#define NFRAMES  509
#define NTHREADS 256

// 1 - exp(-1/441), 1 - exp(-1/4410), computed in double, rounded to f32
#define A_COEFF 0.0022650046943f
#define R_COEFF 0.00022673165872f
#define DB2LIN_LOG2 0.16609640474436812f   // log2(10)/20

__device__ __forceinline__ int rev4_12(int i) {
    unsigned r = __brev((unsigned)i) >> 20;          // 12-bit bit-reversal
    return (int)(((r & 0x555u) << 1) | ((r >> 1) & 0x555u)); // fix pair order -> base-4 digit reversal
}

__device__ __forceinline__ float2 cmulf(float2 a, float2 b) {
    return make_float2(a.x * b.x - a.y * b.y, a.x * b.y + a.y * b.x);
}

__device__ __forceinline__ float2 twget(const float2* tw, int j) {
    // table holds exp(-2*pi*i*j/N) for j in [0, N/2); use tw[j+N/2] = -tw[j]
    float2 w = tw[j & (NHALF - 1)];
    if (j & NHALF) { w.x = -w.x; w.y = -w.y; }
    return w;
}

__device__ __forceinline__ void fill_tw(float2* tw, int tid) {
    for (int j = tid; j < NHALF; j += NTHREADS) {
        float ang = (float)j * -1.5339807878856412e-3f;  // -2*pi/4096
        float sv, cv;
        sincosf(ang, &sv, &cv);
        tw[j] = make_float2(cv, sv);
    }
}

// In-place radix-4 DIT FFT, input must be in base-4 digit-reversed order.
// INV=0: forward (e^{-i}); INV=1: unnormalized inverse (e^{+i}).
template <int INV>
__device__ void fft4096(float2* s, const float2* tw, int tid) {
#pragma unroll
    for (int st = 0; st < 6; ++st) {
        const int quarter = 1 << (2 * st);
#pragma unroll
        for (int bb = 0; bb < NFFT / 4; bb += NTHREADS) {
            const int b   = bb + tid;
            const int pos = b & (quarter - 1);
            const int grp = b >> (2 * st);
            const int base = (grp << (2 * st + 2)) + pos;
            const int ts = pos << (10 - 2 * st);     // pos * (N/m)
            float2 w1 = twget(tw, ts);
            float2 w2 = twget(tw, 2 * ts);
            float2 w3 = twget(tw, 3 * ts);
            if (INV) { w1.y = -w1.y; w2.y = -w2.y; w3.y = -w3.y; }
            float2 x0 = s[base];
            float2 x1 = s[base + quarter];
            float2 x2 = s[base + 2 * quarter];
            float2 x3 = s[base + 3 * quarter];
            float2 a1 = cmulf(x1, w1);
            float2 a2 = cmulf(x2, w2);
            float2 a3 = cmulf(x3, w3);
            float t0x = x0.x + a2.x, t0y = x0.y + a2.y;
            float t1x = x0.x - a2.x, t1y = x0.y - a2.y;
            float t2x = a1.x + a3.x, t2y = a1.y + a3.y;
            float t3x = a1.x - a3.x, t3y = a1.y - a3.y;
            // rotate t3 by -i (fwd) / +i (inv)
            float r3x = INV ? -t3y : t3y;
            float r3y = INV ? t3x : -t3x;
            s[base]               = make_float2(t0x + t2x, t0y + t2y);
            s[base + quarter]     = make_float2(t1x + r3x, t1y + r3y);
            s[base + 2 * quarter] = make_float2(t0x - t2x, t0y - t2y);
            s[base + 3 * quarter] = make_float2(t1x - r3x, t1y - r3y);
        }
        __syncthreads();
    }
}

// ---------------- kernel 1: STFT + per-bin gain-reduction (dB) ----------------
__global__ __launch_bounds__(NTHREADS) void k_fwd(
    const float* __restrict__ audio, const float* __restrict__ window,
    const float* __restrict__ thr, const float* __restrict__ ratio,
    const float* __restrict__ knee, float* __restrict__ gr)
{
    __shared__ float2 s[NFFT];
    __shared__ float2 tw[NHALF];
    const int tid = threadIdx.x;
    const int blk = blockIdx.x;
    const int bc = blk / NFRAMES;
    const int f  = blk - bc * NFRAMES;
    const float* src = audio + (size_t)bc * NSAMP + (size_t)f * NHOP;

    fill_tw(tw, tid);
    for (int i = tid; i < NFFT; i += NTHREADS) {
        float x = src[i] * window[i];
        s[rev4_12(i)] = make_float2(x, 0.f);
    }
    __syncthreads();
    fft4096<0>(s, tw, tid);

    float* gp = gr + ((size_t)bc * NFRAMES + f) * NK;
    for (int k = tid; k < NK; k += NTHREADS) {
        float2 X = s[k];
        float a = sqrtf(X.x * X.x + X.y * X.y);
        float mag_db = 20.0f * log10f(fmaxf(a, 1e-8f));
        float th = thr[k], ra = ratio[k], kw = knee[k];
        float ks = th - 0.5f * kw;
        float ke = th + 0.5f * kw;
        float over = mag_db - th;
        float slope = 1.0f - 1.0f / ra;
        float hard = (mag_db < th) ? 0.0f : over * slope;
        float kf = fminf(fmaxf((mag_db - ks) / kw, 0.0f), 1.0f);
        float kneeg = kf * kf * over * slope;
        gp[k] = (mag_db >= ks && mag_db <= ke) ? kneeg : hard;
    }
}

// ---------- kernel 2: attack/release scan over frames; gr -> linear gain ----------
// gain = env_c * 10^(mk/20)   (the -20log10(env) / 10^(../20) pair cancels)
__global__ __launch_bounds__(NTHREADS) void k_smooth(
    float* __restrict__ gr, const float* __restrict__ makeup)
{
    int gid = blockIdx.x * NTHREADS + threadIdx.x;
    if (gid >= NBC * NK) return;
    int bc = gid / NK;
    int k  = gid - bc * NK;
    float mkLin = exp2f(makeup[k] * DB2LIN_LOG2);   // 10^(mk/20)
    float* p = gr + (size_t)bc * NFRAMES * NK + k;

    float env = 0.f;
    float nextg = p[0];
#pragma unroll 4
    for (int f = 0; f < NFRAMES; ++f) {
        float g = nextg;
        if (f + 1 < NFRAMES) nextg = p[(size_t)(f + 1) * NK];  // prefetch (indep of env)
        float tgt = exp2f(g * -DB2LIN_LOG2);                   // 10^(-g/20)
        float coeff = (tgt < env) ? A_COEFF : R_COEFF;
        env = fmaf(coeff, tgt - env, env);
        float envc = fmaxf(env, 1e-8f);
        p[(size_t)f * NK] = envc * mkLin;
    }
}

// ------- kernel 3: recompute FFT, scale bins, inverse FFT, overlap-add -------
// pass r handles frames f ≡ r (mod 4): output ranges are disjoint -> plain +=
__global__ __launch_bounds__(NTHREADS) void k_inv(
    const float* __restrict__ audio, const float* __restrict__ window,
    const float* __restrict__ gains, float* __restrict__ out,
    int pass, int nfp)
{
    __shared__ float2 s[NFFT];
    __shared__ float2 tw[NHALF];
    const int tid = threadIdx.x;
    const int blk = blockIdx.x;
    const int bc = blk / nfp;
    const int fi = blk - bc * nfp;
    const int f = pass + fi * 4;
    const float* src = audio + (size_t)bc * NSAMP + (size_t)f * NHOP;

    fill_tw(tw, tid);
    for (int i = tid; i < NFFT; i += NTHREADS) {
        float x = src[i] * window[i];
        s[rev4_12(i)] = make_float2(x, 0.f);
    }
    __syncthreads();
    fft4096<0>(s, tw, tid);

    // scale half-spectrum, mirror hermitian half
    const float* gp = gains + ((size_t)bc * NFRAMES + f) * NK;
    for (int k = tid; k < NK; k += NTHREADS) {
        float2 X = s[k];
        float a = sqrtf(X.x * X.x + X.y * X.y);
        float g = gp[k];
        float2 cf;
        if (a >= 1e-8f) {
            cf = make_float2(g * X.x, g * X.y);
        } else if (a > 0.f) {
            float sc = g * 1e-8f / a;         // comp_mag = g*1e-8, keep phase
            cf = make_float2(sc * X.x, sc * X.y);
        } else {
            cf = make_float2(g * 1e-8f, 0.f); // angle(0)=0 -> real
        }
        s[k] = cf;
        if (k > 0 && k < NFFT / 2) s[NFFT - k] = make_float2(cf.x, -cf.y);
    }
    __syncthreads();

    // digit-reverse permute (involution) then inverse FFT
    for (int i = tid; i < NFFT; i += NTHREADS) {
        int j = rev4_12(i);
        if (j > i) { float2 t = s[i]; s[i] = s[j]; s[j] = t; }
    }
    __syncthreads();
    fft4096<1>(s, tw, tid);

    float* dst = out + (size_t)bc * NSAMP + (size_t)f * NHOP;
    const float invn = 1.0f / (float)NFFT;
    for (int i = tid; i < NFFT; i += NTHREADS) {
        dst[i] += s[i].x * invn * window[i];
    }
}

extern "C" void kernel_launch(void* const* d_in, const int* in_sizes, int n_in,
                              void* d_out, int out_size, void* d_ws, size_t ws_size,
                              hipStream_t stream)
{
    const float* audio  = (const float*)d_in[0];
    const float* window = (const float*)d_in[1];
    const float* thr    = (const float*)d_in[2];
    const float* ratio  = (const float*)d_in[3];
    const float* makeup = (const float*)d_in[4];
    const float* knee   = (const float*)d_in[5];
    float* out = (float*)d_out;
    float* gr  = (float*)d_ws;   // NBC*NFRAMES*NK floats ~= 64 MiB

    hipMemsetAsync(d_out, 0, (size_t)out_size * sizeof(float), stream);

    dim3 blk(NTHREADS);
    k_fwd<<<dim3(NBC * NFRAMES), blk, 0, stream>>>(audio, window, thr, ratio, knee, gr);

    int nthr = NBC * NK;
    k_smooth<<<dim3((nthr + NTHREADS - 1) / NTHREADS), blk, 0, stream>>>(gr, makeup);

    for (int pass = 0; pass < 4; ++pass) {
        int nfp = (NFRAMES - pass + 3) / 4;   // frames in this pass
        k_inv<<<dim3(NBC * nfp), blk, 0, stream>>>(audio, window, gr, out, pass, nfp);
    }
}

// Round 4
// 376.987 us; speedup vs baseline: 1.9948x; 1.9948x over previous
//
#include <hip/hip_runtime.h>

#define NFFT     4096
#define NC       2048      // complex FFT length (real-packed)
#define NHOP     1024
#define NK       2049
#define NBC      16
#define NSAMP    524288
#define NFRAMES  509
#define NT       256

#define A_COEFF 0.0022650046943f     // 1 - exp(-1/441)
#define R_COEFF 0.00022673165872f    // 1 - exp(-1/4410)
#define DB2LIN_LOG2 0.16609640474436812f  // log2(10)/20
#define PI_D 3.14159265358979323846264338327950288

// LDS swizzle: ~2-way max at every FFT stage (was 8..32-way)
#define SW(e) ((e) + 7*((e)>>5))
#define SWSZ 2489      // SW(2047)+1
#define TWSZ 682       // per-stage twiddle tables: 512+128+32+8+2

__device__ __forceinline__ int rev11(int i){ return (int)(__brev((unsigned)i) >> 21); }
__device__ __forceinline__ float2 cmul(float2 a, float2 b){
    return make_float2(a.x*b.x - a.y*b.y, a.x*b.y + a.y*b.x);
}
__device__ __forceinline__ float2 f2add(float2 a, float2 b){ return make_float2(a.x+b.x, a.y+b.y); }
__device__ __forceinline__ float2 f2sub(float2 a, float2 b){ return make_float2(a.x-b.x, a.y-b.y); }

// ---------- forward: DIF radix-4 (merged radix-2 pairs) m=512,128,32,8,2 + radix-2 span1.
// natural-order input -> output[p] = Z[rev11(p)]
__device__ __forceinline__ void fft_fwd(float2* s, const float2* twl, int tid){
    const int offs[5] = {0, 512, 640, 672, 680};
#pragma unroll
    for (int st = 0; st < 5; ++st) {
        const int lm = 9 - 2*st;
        const int m  = 1 << lm;
#pragma unroll
        for (int it = 0; it < 2; ++it) {
            int b   = it*NT + tid;
            int pos = b & (m-1);
            int grp = b >> lm;
            int base = (grp << (lm+2)) + pos;
            float2 W  = twl[offs[st] + pos];
            float2 W2 = cmul(W, W);
            float2 W3 = cmul(W2, W);
            float2 d0 = s[SW(base)];
            float2 d1 = s[SW(base+m)];
            float2 d2 = s[SW(base+2*m)];
            float2 d3 = s[SW(base+3*m)];
            float2 A  = f2add(d0, d2), B  = f2add(d1, d3);
            float2 C  = f2sub(d0, d2), Dt = f2sub(d1, d3);
            float2 D  = make_float2(Dt.y, -Dt.x);          // -i*Dt
            s[SW(base)]       = f2add(A, B);
            s[SW(base+m)]     = cmul(f2sub(A, B), W2);
            s[SW(base+2*m)]   = cmul(f2add(C, D), W);
            s[SW(base+3*m)]   = cmul(f2sub(C, D), W3);
        }
        __syncthreads();
    }
#pragma unroll
    for (int it = 0; it < 4; ++it) {                        // radix-2 span 1, w=1
        int b = it*NT + tid;
        int e0 = SW(2*b), e1 = SW(2*b+1);
        float2 a = s[e0], c = s[e1];
        s[e0] = f2add(a, c);
        s[e1] = f2sub(a, c);
    }
    __syncthreads();
}

// ---------- inverse: DIT mirror (bit-reversed input -> natural output), unnormalized
__device__ __forceinline__ void fft_inv(float2* s, const float2* twl, int tid){
#pragma unroll
    for (int it = 0; it < 4; ++it) {                        // radix-2 span 1 first
        int b = it*NT + tid;
        int e0 = SW(2*b), e1 = SW(2*b+1);
        float2 a = s[e0], c = s[e1];
        s[e0] = f2add(a, c);
        s[e1] = f2sub(a, c);
    }
    __syncthreads();
    const int offs[5] = {0, 512, 640, 672, 680};
#pragma unroll
    for (int st = 4; st >= 0; --st) {
        const int lm = 9 - 2*st;
        const int m  = 1 << lm;
#pragma unroll
        for (int it = 0; it < 2; ++it) {
            int b   = it*NT + tid;
            int pos = b & (m-1);
            int grp = b >> lm;
            int base = (grp << (lm+2)) + pos;
            float2 W = twl[offs[st] + pos]; W.y = -W.y;     // conj for inverse
            float2 W2 = cmul(W, W);
            float2 W3 = cmul(W2, W);
            float2 x0 = s[SW(base)];
            float2 X1 = s[SW(base+2*m)];                    // swapped loads (bit-rev input)
            float2 X2 = s[SW(base+m)];
            float2 X3 = s[SW(base+3*m)];
            float2 a1 = cmul(X1, W), a2 = cmul(X2, W2), a3 = cmul(X3, W3);
            float2 t0 = f2add(x0, a2), t1 = f2sub(x0, a2);
            float2 t2 = f2add(a1, a3), t3 = f2sub(a1, a3);
            s[SW(base)]     = f2add(t0, t2);
            s[SW(base+m)]   = make_float2(t1.x - t3.y, t1.y + t3.x);  // t1 + i*t3
            s[SW(base+2*m)] = f2sub(t0, t2);
            s[SW(base+3*m)] = make_float2(t1.x + t3.y, t1.y - t3.x);  // t1 - i*t3
        }
        __syncthreads();
    }
}

__device__ __forceinline__ float gr_of(float a, float th, float ra, float kw){
    float mag_db = 20.0f * log10f(fmaxf(a, 1e-8f));
    float ks = th - 0.5f*kw, ke = th + 0.5f*kw;
    float over  = mag_db - th;
    float slope = 1.0f - 1.0f/ra;
    float hard  = (mag_db < th) ? 0.0f : over*slope;
    float kf    = fminf(fmaxf((mag_db - ks)/kw, 0.0f), 1.0f);
    float kneeg = kf*kf*over*slope;
    return (mag_db >= ks && mag_db <= ke) ? kneeg : hard;
}

__device__ __forceinline__ float2 scale_bin(float2 X, float g){
    float a = sqrtf(X.x*X.x + X.y*X.y);
    if (a >= 1e-8f) return make_float2(g*X.x, g*X.y);
    if (a > 0.f)  { float sc = g*1e-8f/a; return make_float2(sc*X.x, sc*X.y); }
    return make_float2(g*1e-8f, 0.f);
}

// ---------------- init: twiddle tables (double precision, once per launch) ----------------
__global__ __launch_bounds__(NT) void k_init(float2* __restrict__ twg, float2* __restrict__ wpack){
    int i = blockIdx.x*NT + threadIdx.x;
    if (i < TWSZ) {
        int st, off;
        if (i < 512)      { st = 0; off = 0;   }
        else if (i < 640) { st = 1; off = 512; }
        else if (i < 672) { st = 2; off = 640; }
        else if (i < 680) { st = 3; off = 672; }
        else              { st = 4; off = 680; }
        long long pos = i - off;
        double ang = -PI_D * (double)(pos << (2*st)) / 1024.0;   // E(pos*4^st/2048)
        twg[i] = make_float2((float)cos(ang), (float)sin(ang));
    } else if (i < TWSZ + NK) {
        int k = i - TWSZ;
        double ang = -PI_D * (double)k / 2048.0;                 // E(k/4096)
        wpack[k] = make_float2((float)cos(ang), (float)sin(ang));
    }
}

// ---------------- kernel 1: real-packed STFT + gain-reduction (dB, scrambled slots) ----------------
__global__ __launch_bounds__(NT) void k_fwd(
    const float* __restrict__ audio, const float* __restrict__ window,
    const float* __restrict__ thr, const float* __restrict__ ratio,
    const float* __restrict__ knee, const float2* __restrict__ twg,
    const float2* __restrict__ wpack, float* __restrict__ gr,
    float2* __restrict__ spec, int storeSpec)
{
    __shared__ float2 s[SWSZ];
    __shared__ float2 twl[TWSZ];
    const int tid = threadIdx.x;
    const int blk = blockIdx.x;
    const int bc  = blk / NFRAMES;
    const int f   = blk - bc*NFRAMES;

    for (int i = tid; i < TWSZ; i += NT) twl[i] = twg[i];

    const float2* src2 = (const float2*)(audio + (size_t)bc*NSAMP + (size_t)f*NHOP);
    const float2* win2 = (const float2*)window;
    for (int n = tid; n < NC; n += NT) {
        float2 u = src2[n], w = win2[n];
        s[SW(n)] = make_float2(u.x*w.x, u.y*w.y);    // z[n] = x[2n]w + i x[2n+1]w
    }
    __syncthreads();
    fft_fwd(s, twl, tid);

    const size_t row = ((size_t)bc*NFRAMES + f) * NK;
    if (storeSpec) {
        float2* sp = spec + ((size_t)bc*NFRAMES + f) * NC;
        for (int p = tid; p < NC; p += NT) sp[p] = s[SW(p)];
    }
#pragma unroll
    for (int j = 0; j < 4; ++j) {
        int p  = 2*(tid + NT*j);          // even slots: k = rev11(p) < 1024
        int k  = rev11(p);
        int k2 = 2048 - k;
        int p2 = rev11(k2 & 2047);
        float2 Zk  = s[SW(p)];
        float2 Zk2 = s[SW(p2)];
        float2 Ze = make_float2(0.5f*(Zk.x + Zk2.x), 0.5f*(Zk.y - Zk2.y));
        float2 Zo = make_float2(0.5f*(Zk.y + Zk2.y), -0.5f*(Zk.x - Zk2.x));
        float2 W  = wpack[k];
        float2 V  = cmul(W, Zo);
        float2 Xk  = f2add(Ze, V);                                    // X[k]
        float2 Xk2 = make_float2(Ze.x - V.x, V.y - Ze.y);             // X[2048-k] = conj(Ze-V)
        int slot2 = (k == 0) ? 2048 : p2;
        gr[row + p]     = gr_of(sqrtf(Xk.x*Xk.x + Xk.y*Xk.y),   thr[k],  ratio[k],  knee[k]);
        gr[row + slot2] = gr_of(sqrtf(Xk2.x*Xk2.x + Xk2.y*Xk2.y), thr[k2], ratio[k2], knee[k2]);
    }
    if (tid == 0) {   // self-paired bin k=1024 lives at slot 1: X[1024] = conj(Z[1024])
        float2 Z = s[SW(1)];
        gr[row + 1] = gr_of(sqrtf(Z.x*Z.x + Z.y*Z.y), thr[1024], ratio[1024], knee[1024]);
    }
}

// ---------------- kernel 2: attack/release scan; gr(dB) -> linear gain, in-place ----------------
__global__ __launch_bounds__(NT) void k_smooth(
    float* __restrict__ gr, const float* __restrict__ makeup)
{
    int gid = blockIdx.x*NT + threadIdx.x;
    if (gid >= NBC*NK) return;
    int bc   = gid / NK;
    int slot = gid - bc*NK;
    int bin  = (slot < 2048) ? rev11(slot) : 2048;
    float mkLin = exp2f(makeup[bin] * DB2LIN_LOG2);   // 10^(mk/20)
    float* p = gr + (size_t)bc*NFRAMES*NK + slot;

    float env = 0.f;
    float nextg = p[0];
#pragma unroll 4
    for (int f = 0; f < NFRAMES; ++f) {
        float g = nextg;
        if (f + 1 < NFRAMES) nextg = p[(size_t)(f+1)*NK];
        float tgt = exp2f(g * -DB2LIN_LOG2);          // 10^(-g/20)
        float coeff = (tgt < env) ? A_COEFF : R_COEFF;
        env = fmaf(coeff, tgt - env, env);
        p[(size_t)f*NK] = fmaxf(env, 1e-8f) * mkLin;  // linear gain (log/exp pair cancels)
    }
}

// ---------------- kernel 3: scale bins, inverse real-packed FFT, overlap-add ----------------
template<int HASSPEC>
__global__ __launch_bounds__(NT) void k_inv(
    const float* __restrict__ audio, const float* __restrict__ window,
    const float* __restrict__ gains, const float2* __restrict__ twg,
    const float2* __restrict__ wpack, const float2* __restrict__ spec,
    float* __restrict__ out, int pass, int nfp)
{
    __shared__ float2 s[SWSZ];
    __shared__ float2 twl[TWSZ];
    const int tid = threadIdx.x;
    const int blk = blockIdx.x;
    const int bc  = blk / nfp;
    const int fi  = blk - bc*nfp;
    const int f   = pass + 4*fi;

    for (int i = tid; i < TWSZ; i += NT) twl[i] = twg[i];
    const float2* win2 = (const float2*)window;

    if (HASSPEC) {
        const float2* sp = spec + ((size_t)bc*NFRAMES + f) * NC;
        for (int p = tid; p < NC; p += NT) s[SW(p)] = sp[p];
        __syncthreads();
    } else {
        const float2* src2 = (const float2*)(audio + (size_t)bc*NSAMP + (size_t)f*NHOP);
        for (int n = tid; n < NC; n += NT) {
            float2 u = src2[n], w = win2[n];
            s[SW(n)] = make_float2(u.x*w.x, u.y*w.y);
        }
        __syncthreads();
        fft_fwd(s, twl, tid);
    }

    const float* g = gains + ((size_t)bc*NFRAMES + f) * NK;
#pragma unroll
    for (int j = 0; j < 4; ++j) {
        int p  = 2*(tid + NT*j);
        int k  = rev11(p);
        int k2 = 2048 - k;
        int p2 = rev11(k2 & 2047);
        float2 Zk  = s[SW(p)];
        float2 Zk2 = s[SW(p2)];
        float2 Ze = make_float2(0.5f*(Zk.x + Zk2.x), 0.5f*(Zk.y - Zk2.y));
        float2 Zo = make_float2(0.5f*(Zk.y + Zk2.y), -0.5f*(Zk.x - Zk2.x));
        float2 W  = wpack[k];
        float2 V  = cmul(W, Zo);
        float2 Xk  = f2add(Ze, V);
        float2 Xk2 = make_float2(Ze.x - V.x, V.y - Ze.y);
        int slot2 = (k == 0) ? 2048 : p2;
        float2 XSk  = scale_bin(Xk,  g[p]);
        float2 XSk2 = scale_bin(Xk2, g[slot2]);
        // repack: Z'[k] = E + i*conj(W)*P ; Z'[k2] = conj(E) + i*W*conj(P)
        float2 E = make_float2(0.5f*(XSk.x + XSk2.x), 0.5f*(XSk.y - XSk2.y));
        float2 P = make_float2(0.5f*(XSk.x - XSk2.x), 0.5f*(XSk.y + XSk2.y));
        float2 Wc = make_float2(W.x, -W.y);
        float2 Q  = cmul(Wc, P);
        float2 Pc = make_float2(P.x, -P.y);
        float2 R  = cmul(W, Pc);
        s[SW(p)]  = make_float2(E.x - Q.y, E.y + Q.x);
        s[SW(p2)] = make_float2(E.x - R.y, R.x - E.y);
    }
    if (tid == 0) {   // self-paired bin 1024 at slot 1: Z' = conj(scale(conj(Z)))
        float2 Z  = s[SW(1)];
        float2 X  = make_float2(Z.x, -Z.y);
        float2 XS = scale_bin(X, g[1]);
        s[SW(1)] = make_float2(XS.x, -XS.y);
    }
    __syncthreads();
    fft_inv(s, twl, tid);

    float2* dst2 = (float2*)(out + (size_t)bc*NSAMP + (size_t)f*NHOP);
    const float invn = 1.0f/2048.0f;
    for (int n = tid; n < NC; n += NT) {
        float2 z = s[SW(n)];
        float2 w = win2[n];
        float2 o = dst2[n];
        o.x += z.x * w.x * invn;
        o.y += z.y * w.y * invn;
        dst2[n] = o;
    }
}

extern "C" void kernel_launch(void* const* d_in, const int* in_sizes, int n_in,
                              void* d_out, int out_size, void* d_ws, size_t ws_size,
                              hipStream_t stream)
{
    const float* audio  = (const float*)d_in[0];
    const float* window = (const float*)d_in[1];
    const float* thr    = (const float*)d_in[2];
    const float* ratio  = (const float*)d_in[3];
    const float* makeup = (const float*)d_in[4];
    const float* knee   = (const float*)d_in[5];
    float* out = (float*)d_out;

    float2* twg   = (float2*)d_ws;
    float2* wpack = twg + TWSZ;
    float*  gr    = (float*)((char*)d_ws + 32768);
    size_t grBytes = (size_t)NBC*NFRAMES*NK*sizeof(float);
    float2* spec  = (float2*)((char*)d_ws + 32768 + grBytes);
    size_t need = 32768 + grBytes + (size_t)NBC*NFRAMES*NC*sizeof(float2);
    int hasSpec = (ws_size >= need) ? 1 : 0;

    hipMemsetAsync(d_out, 0, (size_t)out_size*sizeof(float), stream);

    k_init<<<dim3((TWSZ + NK + NT - 1)/NT), dim3(NT), 0, stream>>>(twg, wpack);
    k_fwd<<<dim3(NBC*NFRAMES), dim3(NT), 0, stream>>>(
        audio, window, thr, ratio, knee, twg, wpack, gr, spec, hasSpec);
    k_smooth<<<dim3((NBC*NK + NT - 1)/NT), dim3(NT), 0, stream>>>(gr, makeup);
    for (int pass = 0; pass < 4; ++pass) {
        int nfp = (NFRAMES - pass + 3) / 4;
        if (hasSpec)
            k_inv<1><<<dim3(NBC*nfp), dim3(NT), 0, stream>>>(
                audio, window, gr, twg, wpack, spec, out, pass, nfp);
        else
            k_inv<0><<<dim3(NBC*nfp), dim3(NT), 0, stream>>>(
                audio, window, gr, twg, wpack, spec, out, pass, nfp);
    }
}

// Round 5
// 248.293 us; speedup vs baseline: 3.0288x; 1.5183x over previous
//
#include <hip/hip_runtime.h>

#define NFFT     4096
#define NC       2048      // complex FFT length (real-packed)
#define NHOP     1024
#define NK       2049
#define NBC      16
#define NSAMP    524288
#define NFRAMES  509
#define NT       256

#define A_COEFF 0.0022650046943f     // 1 - exp(-1/441)
#define R_COEFF 0.00022673165872f    // 1 - exp(-1/4410)
#define DB2LIN_LOG2 0.16609640474436812f  // log2(10)/20
#define PI_D 3.14159265358979323846264338327950288

// LDS swizzle: ~2-way max at every FFT stage
#define SW(e) ((e) + 7*((e)>>5))
#define SWSZ 2489      // SW(2047)+1
#define TWSZ 682       // per-stage twiddle tables: 512+128+32+8+2 (last 2 unused now)
#define WSHDR 131072   // ws header bytes: twg @0, wpack @16384, params @49152

__device__ __forceinline__ int rev11(int i){ return (int)(__brev((unsigned)i) >> 21); }
__device__ __forceinline__ float2 cmul(float2 a, float2 b){
    return make_float2(a.x*b.x - a.y*b.y, a.x*b.y + a.y*b.x);
}
__device__ __forceinline__ float2 f2add(float2 a, float2 b){ return make_float2(a.x+b.x, a.y+b.y); }
__device__ __forceinline__ float2 f2sub(float2 a, float2 b){ return make_float2(a.x-b.x, a.y-b.y); }

#define RSQRT2 0.70710678118654752f

// ---------- forward: DIF radix-4 m=512,128,32,8 + fused register radix-8 tail.
// natural-order input -> output[p] = Z[rev11(p)]
__device__ __forceinline__ void fft_fwd(float2* s, const float2* twl, int tid){
    const int offs[4] = {0, 512, 640, 672};
#pragma unroll
    for (int st = 0; st < 4; ++st) {
        const int lm = 9 - 2*st;
        const int m  = 1 << lm;
#pragma unroll
        for (int it = 0; it < 2; ++it) {
            int b   = it*NT + tid;
            int pos = b & (m-1);
            int grp = b >> lm;
            int base = (grp << (lm+2)) + pos;
            float2 W  = twl[offs[st] + pos];
            float2 W2 = cmul(W, W);
            float2 W3 = cmul(W2, W);
            float2 d0 = s[SW(base)];
            float2 d1 = s[SW(base+m)];
            float2 d2 = s[SW(base+2*m)];
            float2 d3 = s[SW(base+3*m)];
            float2 A  = f2add(d0, d2), B  = f2add(d1, d3);
            float2 C  = f2sub(d0, d2), Dt = f2sub(d1, d3);
            float2 D  = make_float2(Dt.y, -Dt.x);          // -i*Dt
            s[SW(base)]       = f2add(A, B);
            s[SW(base+m)]     = cmul(f2sub(A, B), W2);
            s[SW(base+2*m)]   = cmul(f2add(C, D), W);
            s[SW(base+3*m)]   = cmul(f2sub(C, D), W3);
        }
        __syncthreads();
    }
    // fused tail: radix-4 (m=2) + radix-2 span1, one 8-elem group per thread
    {
        const int g8 = 8*tid;
        float2 d[8];
#pragma unroll
        for (int l = 0; l < 8; ++l) d[l] = s[SW(g8 + l)];
        { // pos=0, W=1
            float2 A = f2add(d[0], d[4]), B = f2add(d[2], d[6]);
            float2 C = f2sub(d[0], d[4]), Dt = f2sub(d[2], d[6]);
            float2 D = make_float2(Dt.y, -Dt.x);
            d[0] = f2add(A, B);
            d[2] = f2sub(A, B);
            d[4] = f2add(C, D);
            d[6] = f2sub(C, D);
        }
        { // pos=1: W=E(1/8)=c(1,-i..): W=(c,-c), W2=-i, W3=(-c,-c)
            const float c = RSQRT2;
            float2 A = f2add(d[1], d[5]), B = f2add(d[3], d[7]);
            float2 C = f2sub(d[1], d[5]), Dt = f2sub(d[3], d[7]);
            float2 D = make_float2(Dt.y, -Dt.x);
            float2 AB = f2sub(A, B);
            float2 CpD = f2add(C, D);
            float2 CmD = f2sub(C, D);
            d[1] = f2add(A, B);
            d[3] = make_float2(AB.y, -AB.x);                          // *W2 = -i
            d[5] = make_float2(c*(CpD.x + CpD.y), c*(CpD.y - CpD.x)); // *W
            d[7] = make_float2(c*(CmD.y - CmD.x), -c*(CmD.x + CmD.y));// *W3
        }
#pragma unroll
        for (int r = 0; r < 4; ++r) {   // radix-2 span 1
            float2 u = d[2*r], v = d[2*r+1];
            s[SW(g8 + 2*r)]     = f2add(u, v);
            s[SW(g8 + 2*r + 1)] = f2sub(u, v);
        }
    }
    __syncthreads();
}

// ---------- inverse: fused register radix-8 head + DIT radix-4 m=8..512 (unnormalized)
__device__ __forceinline__ void fft_inv(float2* s, const float2* twl, int tid){
    {
        const int g8 = 8*tid;
        float2 d[8];
#pragma unroll
        for (int l = 0; l < 8; ++l) d[l] = s[SW(g8 + l)];
#pragma unroll
        for (int r = 0; r < 4; ++r) {   // radix-2 span 1 first
            float2 u = d[2*r], v = d[2*r+1];
            d[2*r]   = f2add(u, v);
            d[2*r+1] = f2sub(u, v);
        }
        { // pos=0, W=1 : x0=d0, X1=d4, X2=d2, X3=d6
            float2 t0 = f2add(d[0], d[2]), t1 = f2sub(d[0], d[2]);
            float2 t2 = f2add(d[4], d[6]), t3 = f2sub(d[4], d[6]);
            d[0] = f2add(t0, t2);
            d[2] = make_float2(t1.x - t3.y, t1.y + t3.x);
            d[4] = f2sub(t0, t2);
            d[6] = make_float2(t1.x + t3.y, t1.y - t3.x);
        }
        { // pos=1: conjW=(c,c), conjW2=+i, conjW3=(-c,c)
            const float c = RSQRT2;
            float2 x0 = d[1], X1 = d[5], X2 = d[3], X3 = d[7];
            float2 a1 = make_float2(c*(X1.x - X1.y), c*(X1.x + X1.y));
            float2 a2 = make_float2(-X2.y, X2.x);
            float2 a3 = make_float2(-c*(X3.x + X3.y), c*(X3.x - X3.y));
            float2 t0 = f2add(x0, a2), t1 = f2sub(x0, a2);
            float2 t2 = f2add(a1, a3), t3 = f2sub(a1, a3);
            d[1] = f2add(t0, t2);
            d[3] = make_float2(t1.x - t3.y, t1.y + t3.x);
            d[5] = f2sub(t0, t2);
            d[7] = make_float2(t1.x + t3.y, t1.y - t3.x);
        }
#pragma unroll
        for (int l = 0; l < 8; ++l) s[SW(g8 + l)] = d[l];
    }
    __syncthreads();
    const int offs[4] = {0, 512, 640, 672};
#pragma unroll
    for (int st = 3; st >= 0; --st) {
        const int lm = 9 - 2*st;
        const int m  = 1 << lm;
#pragma unroll
        for (int it = 0; it < 2; ++it) {
            int b   = it*NT + tid;
            int pos = b & (m-1);
            int grp = b >> lm;
            int base = (grp << (lm+2)) + pos;
            float2 W = twl[offs[st] + pos]; W.y = -W.y;     // conj for inverse
            float2 W2 = cmul(W, W);
            float2 W3 = cmul(W2, W);
            float2 x0 = s[SW(base)];
            float2 X1 = s[SW(base+2*m)];                    // swapped loads (bit-rev input)
            float2 X2 = s[SW(base+m)];
            float2 X3 = s[SW(base+3*m)];
            float2 a1 = cmul(X1, W), a2 = cmul(X2, W2), a3 = cmul(X3, W3);
            float2 t0 = f2add(x0, a2), t1 = f2sub(x0, a2);
            float2 t2 = f2add(a1, a3), t3 = f2sub(a1, a3);
            s[SW(base)]     = f2add(t0, t2);
            s[SW(base+m)]   = make_float2(t1.x - t3.y, t1.y + t3.x);  // t1 + i*t3
            s[SW(base+2*m)] = f2sub(t0, t2);
            s[SW(base+3*m)] = make_float2(t1.x + t3.y, t1.y - t3.x);  // t1 - i*t3
        }
        __syncthreads();
    }
}

// q = {th, ks, 1/kw, slope}; ke = 2*th - ks
__device__ __forceinline__ float gr_of(float a, float4 q){
    float mag_db = 20.0f * log10f(fmaxf(a, 1e-8f));
    float over = mag_db - q.x;
    float hard = (mag_db < q.x) ? 0.0f : over*q.w;
    float kf = fminf(fmaxf((mag_db - q.y)*q.z, 0.0f), 1.0f);
    float kneeg = kf*kf*over*q.w;
    float ke = 2.0f*q.x - q.y;
    return (mag_db >= q.y && mag_db <= ke) ? kneeg : hard;
}

__device__ __forceinline__ float2 scale_bin(float2 X, float g){
    float a = sqrtf(X.x*X.x + X.y*X.y);
    if (a >= 1e-8f) return make_float2(g*X.x, g*X.y);
    if (a > 0.f)  { float sc = g*1e-8f/a; return make_float2(sc*X.x, sc*X.y); }
    return make_float2(g*1e-8f, 0.f);
}

// ---------------- init: twiddles + packing table + compressor params ----------------
__global__ __launch_bounds__(NT) void k_init(
    const float* __restrict__ thr, const float* __restrict__ ratio,
    const float* __restrict__ knee,
    float2* __restrict__ twg, float2* __restrict__ wpack, float4* __restrict__ params)
{
    int i = blockIdx.x*NT + threadIdx.x;
    if (i < TWSZ) {
        int st, off;
        if (i < 512)      { st = 0; off = 0;   }
        else if (i < 640) { st = 1; off = 512; }
        else if (i < 672) { st = 2; off = 640; }
        else if (i < 680) { st = 3; off = 672; }
        else              { st = 4; off = 680; }
        long long pos = i - off;
        double ang = -PI_D * (double)(pos << (2*st)) / 1024.0;
        twg[i] = make_float2((float)cos(ang), (float)sin(ang));
    } else if (i < TWSZ + NK) {
        int k = i - TWSZ;
        double ang = -PI_D * (double)k / 2048.0;    // E(k/4096)
        wpack[k] = make_float2((float)cos(ang), (float)sin(ang));
    } else if (i < TWSZ + 2*NK) {
        int k = i - TWSZ - NK;
        float th = thr[k], ra = ratio[k], kw = knee[k];
        params[k] = make_float4(th, th - 0.5f*kw, 1.0f/kw, 1.0f - 1.0f/ra);
    }
}

// ---------------- kernel 1: real-packed STFT; spec + gr (thread-order, coalesced) ----------------
template<int STORESPEC>
__global__ __launch_bounds__(NT) void k_fwd(
    const float* __restrict__ audio, const float* __restrict__ window,
    const float4* __restrict__ params, const float2* __restrict__ twg,
    const float2* __restrict__ wpack, float* __restrict__ gr,
    float2* __restrict__ spec)
{
    __shared__ float2 s[SWSZ];
    __shared__ float2 twl[TWSZ];
    const int tid = threadIdx.x;
    const int blk = blockIdx.x;
    const int bc  = blk / NFRAMES;
    const int f   = blk - bc*NFRAMES;

    for (int i = tid; i < TWSZ; i += NT) twl[i] = twg[i];

    const float4* src4 = (const float4*)(audio + (size_t)bc*NSAMP + (size_t)f*NHOP);
    const float4* win4 = (const float4*)window;
    for (int m = tid; m < NC/2; m += NT) {
        float4 u = src4[m], w = win4[m];
        s[SW(2*m)]   = make_float2(u.x*w.x, u.y*w.y);
        s[SW(2*m+1)] = make_float2(u.z*w.z, u.w*w.w);
    }
    __syncthreads();
    fft_fwd(s, twl, tid);

    const size_t row = ((size_t)bc*NFRAMES + f) * NK;
    if (STORESPEC) {
        float4* sp4 = (float4*)(spec + ((size_t)bc*NFRAMES + f) * NC);
        for (int m = tid; m < NC/2; m += NT) {
            float2 a = s[SW(2*m)], b = s[SW(2*m+1)];
            sp4[m] = make_float4(a.x, a.y, b.x, b.y);
        }
    }
#pragma unroll
    for (int j = 0; j < 4; ++j) {
        int p  = 2*(tid + NT*j);          // even slots: k = rev11(p) < 1024
        int k  = rev11(p);
        int k2 = 2048 - k;
        int p2 = rev11(k2 & 2047);
        float2 Zk  = s[SW(p)];
        float2 Zk2 = s[SW(p2)];
        float2 Ze = make_float2(0.5f*(Zk.x + Zk2.x), 0.5f*(Zk.y - Zk2.y));
        float2 Zo = make_float2(0.5f*(Zk.y + Zk2.y), -0.5f*(Zk.x - Zk2.x));
        float2 W  = wpack[k];
        float2 V  = cmul(W, Zo);
        float2 Xk  = f2add(Ze, V);                              // X[k]
        float2 Xk2 = make_float2(Ze.x - V.x, V.y - Ze.y);       // X[2048-k]
        // thread-order storage: coalesced writes
        gr[row + tid + NT*(2*j)]     = gr_of(sqrtf(Xk.x*Xk.x + Xk.y*Xk.y),   params[k]);
        gr[row + tid + NT*(2*j + 1)] = gr_of(sqrtf(Xk2.x*Xk2.x + Xk2.y*Xk2.y), params[k2]);
    }
    if (tid == 0) {   // self-paired bin 1024 (slot p=1): X[1024] = conj(Z[1024]) -> q=2048
        float2 Z = s[SW(1)];
        gr[row + 2048] = gr_of(sqrtf(Z.x*Z.x + Z.y*Z.y), params[1024]);
    }
}

// bin index for thread-order slot q
__device__ __forceinline__ int bin_of_q(int q){
    if (q == 2048) return 1024;
    int jj = q >> 8;             // 0..7
    int t  = q & 255;
    int p  = 2*(t + NT*(jj >> 1));
    int k  = rev11(p);
    return (jj & 1) ? 2048 - k : k;
}

// ---------------- kernel 2: attack/release scan; gr(dB) -> linear gain, in-place ----------------
__global__ __launch_bounds__(NT) void k_smooth(
    float* __restrict__ gr, const float* __restrict__ makeup)
{
    int gid = blockIdx.x*NT + threadIdx.x;
    if (gid >= NBC*NK) return;
    int bc = gid / NK;
    int q  = gid - bc*NK;
    float mkLin = exp2f(makeup[bin_of_q(q)] * DB2LIN_LOG2);   // 10^(mk/20)
    float* p = gr + (size_t)bc*NFRAMES*NK + q;

    float env = 0.f;
    for (int c = 0; c < NFRAMES; c += 8) {
        float v[8];
#pragma unroll
        for (int d = 0; d < 8; ++d)
            if (c + d < NFRAMES) v[d] = p[(size_t)(c+d)*NK];
#pragma unroll
        for (int d = 0; d < 8; ++d)
            if (c + d < NFRAMES) v[d] = exp2f(v[d] * -DB2LIN_LOG2);  // tgt, indep of env
#pragma unroll
        for (int d = 0; d < 8; ++d)
            if (c + d < NFRAMES) {
                float tgt = v[d];
                float coeff = (tgt < env) ? A_COEFF : R_COEFF;
                env = fmaf(coeff, tgt - env, env);
                v[d] = fmaxf(env, 1e-8f) * mkLin;    // linear gain (log/exp pair cancels)
            }
#pragma unroll
        for (int d = 0; d < 8; ++d)
            if (c + d < NFRAMES) p[(size_t)(c+d)*NK] = v[d];
    }
}

// scale + repack bins in LDS (shared by both k_inv modes)
__device__ __forceinline__ void scale_repack(float2* s, const float* __restrict__ g,
                                             const float2* __restrict__ wpack, int tid){
#pragma unroll
    for (int j = 0; j < 4; ++j) {
        int p  = 2*(tid + NT*j);
        int k  = rev11(p);
        int k2 = 2048 - k;
        int p2 = rev11(k2 & 2047);
        float2 Zk  = s[SW(p)];
        float2 Zk2 = s[SW(p2)];
        float2 Ze = make_float2(0.5f*(Zk.x + Zk2.x), 0.5f*(Zk.y - Zk2.y));
        float2 Zo = make_float2(0.5f*(Zk.y + Zk2.y), -0.5f*(Zk.x - Zk2.x));
        float2 W  = wpack[k];
        float2 V  = cmul(W, Zo);
        float2 Xk  = f2add(Ze, V);
        float2 Xk2 = make_float2(Ze.x - V.x, V.y - Ze.y);
        float2 XSk  = scale_bin(Xk,  g[tid + NT*(2*j)]);
        float2 XSk2 = scale_bin(Xk2, g[tid + NT*(2*j + 1)]);
        // repack: Z'[k] = E + i*conj(W)*P ; Z'[k2] = conj(E) + i*W*conj(P)
        float2 E = make_float2(0.5f*(XSk.x + XSk2.x), 0.5f*(XSk.y - XSk2.y));
        float2 P = make_float2(0.5f*(XSk.x - XSk2.x), 0.5f*(XSk.y + XSk2.y));
        float2 Wc = make_float2(W.x, -W.y);
        float2 Q  = cmul(Wc, P);
        float2 Pc = make_float2(P.x, -P.y);
        float2 R  = cmul(W, Pc);
        s[SW(p)]  = make_float2(E.x - Q.y, E.y + Q.x);
        s[SW(p2)] = make_float2(E.x - R.y, R.x - E.y);
    }
    if (tid == 0) {   // self-paired bin 1024 at slot p=1
        float2 Z  = s[SW(1)];
        float2 X  = make_float2(Z.x, -Z.y);
        float2 XS = scale_bin(X, g[2048]);
        s[SW(1)] = make_float2(XS.x, -XS.y);
    }
}

// ---------------- kernel 3 (MODE 0): read spec, scale, ifft, overwrite spec row with ca ----------------
// ---------------- kernel 3 (MODE 1): fallback — recompute fwd FFT, scale, ifft, RMW out (4 passes) ----
template<int MODE>
__global__ __launch_bounds__(NT) void k_inv(
    const float* __restrict__ audio, const float* __restrict__ window,
    const float* __restrict__ gains, const float2* __restrict__ twg,
    const float2* __restrict__ wpack, float2* __restrict__ spec,
    float* __restrict__ out, int pass, int nfp)
{
    __shared__ float2 s[SWSZ];
    __shared__ float2 twl[TWSZ];
    const int tid = threadIdx.x;
    const int blk = blockIdx.x;
    int bc, f;
    if (MODE == 0) { bc = blk / NFRAMES; f = blk - bc*NFRAMES; }
    else           { bc = blk / nfp;     f = pass + 4*(blk - bc*nfp); }

    for (int i = tid; i < TWSZ; i += NT) twl[i] = twg[i];
    const float4* win4 = (const float4*)window;

    float2* sp = spec + ((size_t)bc*NFRAMES + f) * NC;
    if (MODE == 0) {
        const float4* sp4 = (const float4*)sp;
        for (int m = tid; m < NC/2; m += NT) {
            float4 v = sp4[m];
            s[SW(2*m)]   = make_float2(v.x, v.y);
            s[SW(2*m+1)] = make_float2(v.z, v.w);
        }
        __syncthreads();
    } else {
        const float4* src4 = (const float4*)(audio + (size_t)bc*NSAMP + (size_t)f*NHOP);
        for (int m = tid; m < NC/2; m += NT) {
            float4 u = src4[m], w = win4[m];
            s[SW(2*m)]   = make_float2(u.x*w.x, u.y*w.y);
            s[SW(2*m+1)] = make_float2(u.z*w.z, u.w*w.w);
        }
        __syncthreads();
        fft_fwd(s, twl, tid);
    }

    scale_repack(s, gains + ((size_t)bc*NFRAMES + f) * NK, wpack, tid);
    __syncthreads();
    fft_inv(s, twl, tid);

    const float invn = 1.0f/2048.0f;
    if (MODE == 0) {
        float4* dst4 = (float4*)sp;      // overwrite spec row with windowed ifft (ca)
        for (int m = tid; m < NC/2; m += NT) {
            float2 z0 = s[SW(2*m)], z1 = s[SW(2*m+1)];
            float4 w = win4[m];
            dst4[m] = make_float4(z0.x*w.x*invn, z0.y*w.y*invn,
                                  z1.x*w.z*invn, z1.y*w.w*invn);
        }
    } else {
        float2* dst2 = (float2*)(out + (size_t)bc*NSAMP + (size_t)f*NHOP);
        const float2* win2 = (const float2*)window;
        for (int n = tid; n < NC; n += NT) {
            float2 z = s[SW(n)];
            float2 w = win2[n];
            float2 o = dst2[n];
            o.x += z.x * w.x * invn;
            o.y += z.y * w.y * invn;
            dst2[n] = o;
        }
    }
}

// ---------------- kernel 4: overlap-add gather (deterministic, writes every sample once) ----------------
__global__ __launch_bounds__(NT) void k_ola(
    const float* __restrict__ ca, float* __restrict__ out)
{
    const int blk = blockIdx.x;
    const int bc = blk >> 9;          // 512 tiles of 1024 samples
    const int ti = blk & 511;
    const int tid = threadIdx.x;
    float4 acc = make_float4(0.f, 0.f, 0.f, 0.f);
    int flo = ti - 3; if (flo < 0) flo = 0;
    int fhi = ti; if (fhi > NFRAMES - 1) fhi = NFRAMES - 1;
    for (int f = flo; f <= fhi; ++f) {
        const float4* row = (const float4*)(ca + ((size_t)bc*NFRAMES + f) * NFFT);
        float4 v = row[(ti - f)*256 + tid];
        acc.x += v.x; acc.y += v.y; acc.z += v.z; acc.w += v.w;
    }
    ((float4*)(out + (size_t)bc*NSAMP))[ti*256 + tid] = acc;
}

extern "C" void kernel_launch(void* const* d_in, const int* in_sizes, int n_in,
                              void* d_out, int out_size, void* d_ws, size_t ws_size,
                              hipStream_t stream)
{
    const float* audio  = (const float*)d_in[0];
    const float* window = (const float*)d_in[1];
    const float* thr    = (const float*)d_in[2];
    const float* ratio  = (const float*)d_in[3];
    const float* makeup = (const float*)d_in[4];
    const float* knee   = (const float*)d_in[5];
    float* out = (float*)d_out;

    float2* twg    = (float2*)d_ws;
    float2* wpack  = (float2*)((char*)d_ws + 16384);
    float4* params = (float4*)((char*)d_ws + 49152);
    float*  gr     = (float*)((char*)d_ws + WSHDR);
    size_t grBytes = (size_t)NBC*NFRAMES*NK*sizeof(float);
    float2* spec   = (float2*)((char*)d_ws + WSHDR + grBytes);
    size_t need = WSHDR + grBytes + (size_t)NBC*NFRAMES*NC*sizeof(float2);
    int hasSpec = (ws_size >= need) ? 1 : 0;

    dim3 blkd(NT);
    k_init<<<dim3((TWSZ + 2*NK + NT - 1)/NT), blkd, 0, stream>>>(
        thr, ratio, knee, twg, wpack, params);

    if (hasSpec) {
        k_fwd<1><<<dim3(NBC*NFRAMES), blkd, 0, stream>>>(
            audio, window, params, twg, wpack, gr, spec);
        k_smooth<<<dim3((NBC*NK + NT - 1)/NT), blkd, 0, stream>>>(gr, makeup);
        k_inv<0><<<dim3(NBC*NFRAMES), blkd, 0, stream>>>(
            audio, window, gr, twg, wpack, spec, out, 0, 0);
        k_ola<<<dim3(NBC*512), blkd, 0, stream>>>((const float*)spec, out);
    } else {
        hipMemsetAsync(d_out, 0, (size_t)out_size*sizeof(float), stream);
        k_fwd<0><<<dim3(NBC*NFRAMES), blkd, 0, stream>>>(
            audio, window, params, twg, wpack, gr, spec);
        k_smooth<<<dim3((NBC*NK + NT - 1)/NT), blkd, 0, stream>>>(gr, makeup);
        for (int pass = 0; pass < 4; ++pass) {
            int nfp = (NFRAMES - pass + 3) / 4;
            k_inv<1><<<dim3(NBC*nfp), blkd, 0, stream>>>(
                audio, window, gr, twg, wpack, spec, out, pass, nfp);
        }
    }
}

// Round 6
// 219.650 us; speedup vs baseline: 3.4238x; 1.1304x over previous
//
#include <hip/hip_runtime.h>

#define NFFT     4096
#define NC       2048      // complex FFT length (real-packed)
#define NHOP     1024
#define NK       2049
#define NBC      16
#define NSAMP    524288
#define NFRAMES  509
#define NT       256
#define STH      64        // k_smooth block size

#define A_COEFF 0.0022650046943f     // 1 - exp(-1/441)
#define R_COEFF 0.00022673165872f    // 1 - exp(-1/4410)
#define DB2LIN_LOG2 0.16609640474436812f  // log2(10)/20
#define DB_LOG2     6.02059991327962390f  // 20*log10(2)
#define PI_D 3.14159265358979323846264338327950288

// LDS swizzle: ~2-way max at every FFT stage
#define SW(e) ((e) + 7*((e)>>5))
#define SWSZ 2489      // SW(2047)+1  -> 19912 B LDS = 8 blocks/CU
#define TWN  680       // per-stage twiddle tables: 512+128+32+8
// ws header layout (bytes): tw12 f4[680]@0, tw3 f2[680]@12288, wbr f2[1024]@20480,
//                           pa f4[1024]@32768, pb f4[1024]@49152
#define WSHDR 65536

__device__ __forceinline__ int rev11(int i){ return (int)(__brev((unsigned)i) >> 21); }
__device__ __forceinline__ float2 cmul(float2 a, float2 b){
    return make_float2(a.x*b.x - a.y*b.y, a.x*b.y + a.y*b.x);
}
__device__ __forceinline__ float2 f2add(float2 a, float2 b){ return make_float2(a.x+b.x, a.y+b.y); }
__device__ __forceinline__ float2 f2sub(float2 a, float2 b){ return make_float2(a.x-b.x, a.y-b.y); }

#define RSQRT2 0.70710678118654752f

// ---------- forward: DIF radix-4 m=512,128,32,8 (twiddles W,W2,W3 from global/L1)
// + fused register radix-8 tail. natural-order input -> output[p] = Z[rev11(p)]
__device__ __forceinline__ void fft_fwd(float2* s, const float4* __restrict__ tw12,
                                        const float2* __restrict__ tw3t, int tid){
    const int offs[4] = {0, 512, 640, 672};
#pragma unroll
    for (int st = 0; st < 4; ++st) {
        const int lm = 9 - 2*st;
        const int m  = 1 << lm;
#pragma unroll
        for (int it = 0; it < 2; ++it) {
            int b   = it*NT + tid;
            int pos = b & (m-1);
            int grp = b >> lm;
            int base = (grp << (lm+2)) + pos;
            float4 w12 = tw12[offs[st] + pos];
            float2 W  = make_float2(w12.x, w12.y);
            float2 W2 = make_float2(w12.z, w12.w);
            float2 W3 = tw3t[offs[st] + pos];
            float2 d0 = s[SW(base)];
            float2 d1 = s[SW(base+m)];
            float2 d2 = s[SW(base+2*m)];
            float2 d3 = s[SW(base+3*m)];
            float2 A  = f2add(d0, d2), B  = f2add(d1, d3);
            float2 C  = f2sub(d0, d2), Dt = f2sub(d1, d3);
            float2 D  = make_float2(Dt.y, -Dt.x);          // -i*Dt
            s[SW(base)]       = f2add(A, B);
            s[SW(base+m)]     = cmul(f2sub(A, B), W2);
            s[SW(base+2*m)]   = cmul(f2add(C, D), W);
            s[SW(base+3*m)]   = cmul(f2sub(C, D), W3);
        }
        __syncthreads();
    }
    // fused tail: radix-4 (m=2) + radix-2 span1, one 8-elem group per thread
    {
        const int g8 = 8*tid;
        float2 d[8];
#pragma unroll
        for (int l = 0; l < 8; ++l) d[l] = s[SW(g8 + l)];
        { // pos=0, W=1
            float2 A = f2add(d[0], d[4]), B = f2add(d[2], d[6]);
            float2 C = f2sub(d[0], d[4]), Dt = f2sub(d[2], d[6]);
            float2 D = make_float2(Dt.y, -Dt.x);
            d[0] = f2add(A, B);
            d[2] = f2sub(A, B);
            d[4] = f2add(C, D);
            d[6] = f2sub(C, D);
        }
        { // pos=1: W=(c,-c), W2=-i, W3=(-c,-c)
            const float c = RSQRT2;
            float2 A = f2add(d[1], d[5]), B = f2add(d[3], d[7]);
            float2 C = f2sub(d[1], d[5]), Dt = f2sub(d[3], d[7]);
            float2 D = make_float2(Dt.y, -Dt.x);
            float2 AB = f2sub(A, B);
            float2 CpD = f2add(C, D);
            float2 CmD = f2sub(C, D);
            d[1] = f2add(A, B);
            d[3] = make_float2(AB.y, -AB.x);
            d[5] = make_float2(c*(CpD.x + CpD.y), c*(CpD.y - CpD.x));
            d[7] = make_float2(c*(CmD.y - CmD.x), -c*(CmD.x + CmD.y));
        }
#pragma unroll
        for (int r = 0; r < 4; ++r) {   // radix-2 span 1
            float2 u = d[2*r], v = d[2*r+1];
            s[SW(g8 + 2*r)]     = f2add(u, v);
            s[SW(g8 + 2*r + 1)] = f2sub(u, v);
        }
    }
    __syncthreads();
}

// ---------- inverse: fused register radix-8 head + DIT radix-4 m=8..512 (unnormalized)
__device__ __forceinline__ void fft_inv(float2* s, const float4* __restrict__ tw12,
                                        const float2* __restrict__ tw3t, int tid){
    {
        const int g8 = 8*tid;
        float2 d[8];
#pragma unroll
        for (int l = 0; l < 8; ++l) d[l] = s[SW(g8 + l)];
#pragma unroll
        for (int r = 0; r < 4; ++r) {   // radix-2 span 1 first
            float2 u = d[2*r], v = d[2*r+1];
            d[2*r]   = f2add(u, v);
            d[2*r+1] = f2sub(u, v);
        }
        { // pos=0, W=1 : x0=d0, X1=d4, X2=d2, X3=d6
            float2 t0 = f2add(d[0], d[2]), t1 = f2sub(d[0], d[2]);
            float2 t2 = f2add(d[4], d[6]), t3 = f2sub(d[4], d[6]);
            d[0] = f2add(t0, t2);
            d[2] = make_float2(t1.x - t3.y, t1.y + t3.x);
            d[4] = f2sub(t0, t2);
            d[6] = make_float2(t1.x + t3.y, t1.y - t3.x);
        }
        { // pos=1: conjW=(c,c), conjW2=+i, conjW3=(-c,c)
            const float c = RSQRT2;
            float2 x0 = d[1], X1 = d[5], X2 = d[3], X3 = d[7];
            float2 a1 = make_float2(c*(X1.x - X1.y), c*(X1.x + X1.y));
            float2 a2 = make_float2(-X2.y, X2.x);
            float2 a3 = make_float2(-c*(X3.x + X3.y), c*(X3.x - X3.y));
            float2 t0 = f2add(x0, a2), t1 = f2sub(x0, a2);
            float2 t2 = f2add(a1, a3), t3 = f2sub(a1, a3);
            d[1] = f2add(t0, t2);
            d[3] = make_float2(t1.x - t3.y, t1.y + t3.x);
            d[5] = f2sub(t0, t2);
            d[7] = make_float2(t1.x + t3.y, t1.y - t3.x);
        }
#pragma unroll
        for (int l = 0; l < 8; ++l) s[SW(g8 + l)] = d[l];
    }
    __syncthreads();
    const int offs[4] = {0, 512, 640, 672};
#pragma unroll
    for (int st = 3; st >= 0; --st) {
        const int lm = 9 - 2*st;
        const int m  = 1 << lm;
#pragma unroll
        for (int it = 0; it < 2; ++it) {
            int b   = it*NT + tid;
            int pos = b & (m-1);
            int grp = b >> lm;
            int base = (grp << (lm+2)) + pos;
            float4 w12 = tw12[offs[st] + pos];
            float2 W  = make_float2(w12.x, -w12.y);         // conj for inverse
            float2 W2 = make_float2(w12.z, -w12.w);
            float2 W3 = tw3t[offs[st] + pos]; W3.y = -W3.y;
            float2 x0 = s[SW(base)];
            float2 X1 = s[SW(base+2*m)];                    // swapped loads (bit-rev input)
            float2 X2 = s[SW(base+m)];
            float2 X3 = s[SW(base+3*m)];
            float2 a1 = cmul(X1, W), a2 = cmul(X2, W2), a3 = cmul(X3, W3);
            float2 t0 = f2add(x0, a2), t1 = f2sub(x0, a2);
            float2 t2 = f2add(a1, a3), t3 = f2sub(a1, a3);
            s[SW(base)]     = f2add(t0, t2);
            s[SW(base+m)]   = make_float2(t1.x - t3.y, t1.y + t3.x);  // t1 + i*t3
            s[SW(base+2*m)] = f2sub(t0, t2);
            s[SW(base+3*m)] = make_float2(t1.x + t3.y, t1.y - t3.x);  // t1 - i*t3
        }
        __syncthreads();
    }
}

// q = {th, ks, 1/kw, slope}; ke = 2*th - ks
__device__ __forceinline__ float gr_of(float a, float4 q){
    float mag_db = DB_LOG2 * log2f(fmaxf(a, 1e-8f));
    float over = mag_db - q.x;
    float hard = (mag_db < q.x) ? 0.0f : over*q.w;
    float kf = fminf(fmaxf((mag_db - q.y)*q.z, 0.0f), 1.0f);
    float kneeg = kf*kf*over*q.w;
    float ke = 2.0f*q.x - q.y;
    return (mag_db >= q.y && mag_db <= ke) ? kneeg : hard;
}

__device__ __forceinline__ float2 scale_bin(float2 X, float g){
    float a = sqrtf(X.x*X.x + X.y*X.y);
    if (a >= 1e-8f) return make_float2(g*X.x, g*X.y);
    if (a > 0.f)  { float sc = g*1e-8f/a; return make_float2(sc*X.x, sc*X.y); }
    return make_float2(g*1e-8f, 0.f);
}

// ---------------- init: stage twiddles (W,W2,W3) + bit-rev-ordered pack/param tables ----------------
__global__ __launch_bounds__(NT) void k_init(
    const float* __restrict__ thr, const float* __restrict__ ratio,
    const float* __restrict__ knee,
    float4* __restrict__ tw12, float2* __restrict__ tw3t,
    float2* __restrict__ wbr, float4* __restrict__ pa, float4* __restrict__ pb)
{
    int i = blockIdx.x*NT + threadIdx.x;
    if (i < TWN) {
        int st, off;
        if (i < 512)      { st = 0; off = 0;   }
        else if (i < 640) { st = 1; off = 512; }
        else if (i < 672) { st = 2; off = 640; }
        else              { st = 3; off = 672; }
        long long pos = i - off;
        double ang = -PI_D * (double)(pos << (2*st)) / 1024.0;
        tw12[i] = make_float4((float)cos(ang), (float)sin(ang),
                              (float)cos(2.0*ang), (float)sin(2.0*ang));
        tw3t[i] = make_float2((float)cos(3.0*ang), (float)sin(3.0*ang));
    } else if (i < TWN + 1024) {
        int m = i - TWN;
        int k = rev11(2*m);               // bin for even slot p=2m (k<1024)
        int k2 = 2048 - k;                // partner bin (k=0 -> 2048)
        double ang = -PI_D * (double)k / 2048.0;     // E(k/4096)
        wbr[m] = make_float2((float)cos(ang), (float)sin(ang));
        float th = thr[k], ra = ratio[k], kw = knee[k];
        pa[m] = make_float4(th, th - 0.5f*kw, 1.0f/kw, 1.0f - 1.0f/ra);
        th = thr[k2]; ra = ratio[k2]; kw = knee[k2];
        pb[m] = make_float4(th, th - 0.5f*kw, 1.0f/kw, 1.0f - 1.0f/ra);
    }
}

// ---------------- kernel 1: real-packed STFT; spec + gr (thread-order, coalesced) ----------------
template<int STORESPEC>
__global__ __launch_bounds__(NT, 8) void k_fwd(
    const float* __restrict__ audio, const float* __restrict__ window,
    const float* __restrict__ thr, const float* __restrict__ ratio,
    const float* __restrict__ knee,
    const float4* __restrict__ tw12, const float2* __restrict__ tw3t,
    const float2* __restrict__ wbr, const float4* __restrict__ pa,
    const float4* __restrict__ pb,
    float* __restrict__ gr, float2* __restrict__ spec)
{
    __shared__ float2 s[SWSZ];
    const int tid = threadIdx.x;
    const int blk = blockIdx.x;
    const int bc  = blk / NFRAMES;
    const int f   = blk - bc*NFRAMES;

    const float4* src4 = (const float4*)(audio + (size_t)bc*NSAMP + (size_t)f*NHOP);
    const float4* win4 = (const float4*)window;
    for (int m = tid; m < NC/2; m += NT) {
        float4 u = src4[m], w = win4[m];
        s[SW(2*m)]   = make_float2(u.x*w.x, u.y*w.y);
        s[SW(2*m+1)] = make_float2(u.z*w.z, u.w*w.w);
    }
    __syncthreads();
    fft_fwd(s, tw12, tw3t, tid);

    const size_t row = ((size_t)bc*NFRAMES + f) * NK;
    if (STORESPEC) {
        float4* sp4 = (float4*)(spec + ((size_t)bc*NFRAMES + f) * NC);
        for (int m = tid; m < NC/2; m += NT) {
            float2 a = s[SW(2*m)], b = s[SW(2*m+1)];
            sp4[m] = make_float4(a.x, a.y, b.x, b.y);
        }
    }
#pragma unroll
    for (int j = 0; j < 4; ++j) {
        int m  = tid + NT*j;
        int p  = 2*m;                     // even slots: k = rev11(p) < 1024
        int k  = rev11(p);
        int p2 = rev11((2048 - k) & 2047);
        float2 Zk  = s[SW(p)];
        float2 Zk2 = s[SW(p2)];
        float2 Ze = make_float2(0.5f*(Zk.x + Zk2.x), 0.5f*(Zk.y - Zk2.y));
        float2 Zo = make_float2(0.5f*(Zk.y + Zk2.y), -0.5f*(Zk.x - Zk2.x));
        float2 W  = wbr[m];
        float2 V  = cmul(W, Zo);
        float2 Xk  = f2add(Ze, V);                              // X[k]
        float2 Xk2 = make_float2(Ze.x - V.x, V.y - Ze.y);       // X[2048-k]
        gr[row + tid + NT*(2*j)]     = gr_of(sqrtf(Xk.x*Xk.x + Xk.y*Xk.y),   pa[m]);
        gr[row + tid + NT*(2*j + 1)] = gr_of(sqrtf(Xk2.x*Xk2.x + Xk2.y*Xk2.y), pb[m]);
    }
    if (tid == 0) {   // self-paired bin 1024 (slot p=1): X[1024] = conj(Z[1024]) -> q=2048
        float2 Z = s[SW(1)];
        float th = thr[1024], ra = ratio[1024], kw = knee[1024];
        float4 q = make_float4(th, th - 0.5f*kw, 1.0f/kw, 1.0f - 1.0f/ra);
        gr[row + 2048] = gr_of(sqrtf(Z.x*Z.x + Z.y*Z.y), q);
    }
}

// bin index for thread-order slot q
__device__ __forceinline__ int bin_of_q(int q){
    if (q == 2048) return 1024;
    int jj = q >> 8;             // 0..7
    int t  = q & 255;
    int p  = 2*(t + NT*(jj >> 1));
    int k  = rev11(p);
    return (jj & 1) ? 2048 - k : k;
}

// ---------------- kernel 2: attack/release scan; gr(dB) -> linear gain, in-place ----------------
__global__ __launch_bounds__(STH) void k_smooth(
    float* __restrict__ gr, const float* __restrict__ makeup)
{
    int gid = blockIdx.x*STH + threadIdx.x;
    if (gid >= NBC*NK) return;
    int bc = gid / NK;
    int q  = gid - bc*NK;
    float mkLin = exp2f(makeup[bin_of_q(q)] * DB2LIN_LOG2);   // 10^(mk/20)
    float* p = gr + (size_t)bc*NFRAMES*NK + q;

    float env = 0.f;
    for (int c = 0; c < NFRAMES; c += 8) {
        float v[8];
#pragma unroll
        for (int d = 0; d < 8; ++d)
            if (c + d < NFRAMES) v[d] = p[(size_t)(c+d)*NK];
#pragma unroll
        for (int d = 0; d < 8; ++d)
            if (c + d < NFRAMES) v[d] = exp2f(v[d] * -DB2LIN_LOG2);  // tgt, indep of env
#pragma unroll
        for (int d = 0; d < 8; ++d)
            if (c + d < NFRAMES) {
                float tgt = v[d];
                float coeff = (tgt < env) ? A_COEFF : R_COEFF;
                env = fmaf(coeff, tgt - env, env);
                v[d] = fmaxf(env, 1e-8f) * mkLin;    // linear gain (log/exp pair cancels)
            }
#pragma unroll
        for (int d = 0; d < 8; ++d)
            if (c + d < NFRAMES) p[(size_t)(c+d)*NK] = v[d];
    }
}

// scale + repack bins in LDS (shared by both k_inv modes)
__device__ __forceinline__ void scale_repack(float2* s, const float* __restrict__ g,
                                             const float2* __restrict__ wbr, int tid){
#pragma unroll
    for (int j = 0; j < 4; ++j) {
        int m  = tid + NT*j;
        int p  = 2*m;
        int k  = rev11(p);
        int p2 = rev11((2048 - k) & 2047);
        float2 Zk  = s[SW(p)];
        float2 Zk2 = s[SW(p2)];
        float2 Ze = make_float2(0.5f*(Zk.x + Zk2.x), 0.5f*(Zk.y - Zk2.y));
        float2 Zo = make_float2(0.5f*(Zk.y + Zk2.y), -0.5f*(Zk.x - Zk2.x));
        float2 W  = wbr[m];
        float2 V  = cmul(W, Zo);
        float2 Xk  = f2add(Ze, V);
        float2 Xk2 = make_float2(Ze.x - V.x, V.y - Ze.y);
        float2 XSk  = scale_bin(Xk,  g[tid + NT*(2*j)]);
        float2 XSk2 = scale_bin(Xk2, g[tid + NT*(2*j + 1)]);
        // repack: Z'[k] = E + i*conj(W)*P ; Z'[k2] = conj(E) + i*W*conj(P)
        float2 E = make_float2(0.5f*(XSk.x + XSk2.x), 0.5f*(XSk.y - XSk2.y));
        float2 P = make_float2(0.5f*(XSk.x - XSk2.x), 0.5f*(XSk.y + XSk2.y));
        float2 Wc = make_float2(W.x, -W.y);
        float2 Q  = cmul(Wc, P);
        float2 Pc = make_float2(P.x, -P.y);
        float2 R  = cmul(W, Pc);
        s[SW(p)]  = make_float2(E.x - Q.y, E.y + Q.x);
        s[SW(p2)] = make_float2(E.x - R.y, R.x - E.y);
    }
    if (tid == 0) {   // self-paired bin 1024 at slot p=1
        float2 Z  = s[SW(1)];
        float2 X  = make_float2(Z.x, -Z.y);
        float2 XS = scale_bin(X, g[2048]);
        s[SW(1)] = make_float2(XS.x, -XS.y);
    }
}

// ---------------- kernel 3 (MODE 0): read spec, scale, ifft, overwrite spec row with ca ----------------
// ---------------- kernel 3 (MODE 1): fallback — recompute fwd FFT, scale, ifft, RMW out (4 passes) ----
template<int MODE>
__global__ __launch_bounds__(NT, 8) void k_inv(
    const float* __restrict__ audio, const float* __restrict__ window,
    const float* __restrict__ gains,
    const float4* __restrict__ tw12, const float2* __restrict__ tw3t,
    const float2* __restrict__ wbr,
    float2* __restrict__ spec, float* __restrict__ out, int pass, int nfp)
{
    __shared__ float2 s[SWSZ];
    const int tid = threadIdx.x;
    const int blk = blockIdx.x;
    int bc, f;
    if (MODE == 0) { bc = blk / NFRAMES; f = blk - bc*NFRAMES; }
    else           { bc = blk / nfp;     f = pass + 4*(blk - bc*nfp); }

    const float4* win4 = (const float4*)window;
    float2* sp = spec + ((size_t)bc*NFRAMES + f) * NC;
    if (MODE == 0) {
        const float4* sp4 = (const float4*)sp;
        for (int m = tid; m < NC/2; m += NT) {
            float4 v = sp4[m];
            s[SW(2*m)]   = make_float2(v.x, v.y);
            s[SW(2*m+1)] = make_float2(v.z, v.w);
        }
        __syncthreads();
    } else {
        const float4* src4 = (const float4*)(audio + (size_t)bc*NSAMP + (size_t)f*NHOP);
        for (int m = tid; m < NC/2; m += NT) {
            float4 u = src4[m], w = win4[m];
            s[SW(2*m)]   = make_float2(u.x*w.x, u.y*w.y);
            s[SW(2*m+1)] = make_float2(u.z*w.z, u.w*w.w);
        }
        __syncthreads();
        fft_fwd(s, tw12, tw3t, tid);
    }

    scale_repack(s, gains + ((size_t)bc*NFRAMES + f) * NK, wbr, tid);
    __syncthreads();
    fft_inv(s, tw12, tw3t, tid);

    const float invn = 1.0f/2048.0f;
    if (MODE == 0) {
        float4* dst4 = (float4*)sp;      // overwrite spec row with windowed ifft (ca)
        for (int m = tid; m < NC/2; m += NT) {
            float2 z0 = s[SW(2*m)], z1 = s[SW(2*m+1)];
            float4 w = win4[m];
            dst4[m] = make_float4(z0.x*w.x*invn, z0.y*w.y*invn,
                                  z1.x*w.z*invn, z1.y*w.w*invn);
        }
    } else {
        float2* dst2 = (float2*)(out + (size_t)bc*NSAMP + (size_t)f*NHOP);
        const float2* win2 = (const float2*)window;
        for (int n = tid; n < NC; n += NT) {
            float2 z = s[SW(n)];
            float2 w = win2[n];
            float2 o = dst2[n];
            o.x += z.x * w.x * invn;
            o.y += z.y * w.y * invn;
            dst2[n] = o;
        }
    }
}

// ---------------- kernel 4: overlap-add gather (deterministic, writes every sample once) ----------------
__global__ __launch_bounds__(NT) void k_ola(
    const float* __restrict__ ca, float* __restrict__ out)
{
    const int blk = blockIdx.x;
    const int bc = blk >> 9;          // 512 tiles of 1024 samples
    const int ti = blk & 511;
    const int tid = threadIdx.x;
    float4 acc = make_float4(0.f, 0.f, 0.f, 0.f);
    int flo = ti - 3; if (flo < 0) flo = 0;
    int fhi = ti; if (fhi > NFRAMES - 1) fhi = NFRAMES - 1;
    for (int f = flo; f <= fhi; ++f) {
        const float4* row = (const float4*)(ca + ((size_t)bc*NFRAMES + f) * NFFT);
        float4 v = row[(ti - f)*256 + tid];
        acc.x += v.x; acc.y += v.y; acc.z += v.z; acc.w += v.w;
    }
    ((float4*)(out + (size_t)bc*NSAMP))[ti*256 + tid] = acc;
}

extern "C" void kernel_launch(void* const* d_in, const int* in_sizes, int n_in,
                              void* d_out, int out_size, void* d_ws, size_t ws_size,
                              hipStream_t stream)
{
    const float* audio  = (const float*)d_in[0];
    const float* window = (const float*)d_in[1];
    const float* thr    = (const float*)d_in[2];
    const float* ratio  = (const float*)d_in[3];
    const float* makeup = (const float*)d_in[4];
    const float* knee   = (const float*)d_in[5];
    float* out = (float*)d_out;

    float4* tw12 = (float4*)d_ws;
    float2* tw3t = (float2*)((char*)d_ws + 12288);
    float2* wbr  = (float2*)((char*)d_ws + 20480);
    float4* pa   = (float4*)((char*)d_ws + 32768);
    float4* pb   = (float4*)((char*)d_ws + 49152);
    float*  gr   = (float*)((char*)d_ws + WSHDR);
    size_t grBytes = (size_t)NBC*NFRAMES*NK*sizeof(float);
    float2* spec = (float2*)((char*)d_ws + WSHDR + grBytes);
    size_t need = WSHDR + grBytes + (size_t)NBC*NFRAMES*NC*sizeof(float2);
    int hasSpec = (ws_size >= need) ? 1 : 0;

    dim3 blkd(NT);
    k_init<<<dim3((TWN + 1024 + NT - 1)/NT), blkd, 0, stream>>>(
        thr, ratio, knee, tw12, tw3t, wbr, pa, pb);

    if (hasSpec) {
        k_fwd<1><<<dim3(NBC*NFRAMES), blkd, 0, stream>>>(
            audio, window, thr, ratio, knee, tw12, tw3t, wbr, pa, pb, gr, spec);
        k_smooth<<<dim3((NBC*NK + STH - 1)/STH), dim3(STH), 0, stream>>>(gr, makeup);
        k_inv<0><<<dim3(NBC*NFRAMES), blkd, 0, stream>>>(
            audio, window, gr, tw12, tw3t, wbr, spec, out, 0, 0);
        k_ola<<<dim3(NBC*512), blkd, 0, stream>>>((const float*)spec, out);
    } else {
        hipMemsetAsync(d_out, 0, (size_t)out_size*sizeof(float), stream);
        k_fwd<0><<<dim3(NBC*NFRAMES), blkd, 0, stream>>>(
            audio, window, thr, ratio, knee, tw12, tw3t, wbr, pa, pb, gr, spec);
        k_smooth<<<dim3((NBC*NK + STH - 1)/STH), dim3(STH), 0, stream>>>(gr, makeup);
        for (int pass = 0; pass < 4; ++pass) {
            int nfp = (NFRAMES - pass + 3) / 4;
            k_inv<1><<<dim3(NBC*nfp), blkd, 0, stream>>>(
                audio, window, gr, tw12, tw3t, wbr, spec, out, pass, nfp);
        }
    }
}